// Round 11
// baseline (322.202 us; speedup 1.0000x reference)
//
#include <hip/hip_runtime.h>

#define N_NODES 50000
#define N_EDGES 1600000
#define N_GRAPHS 256
#define HID 128

#define NBUCK 256
#define BUCK_SHIFT 8
#define NBUCK_USED ((N_NODES + 255) >> 8)   // 196
#define BINBLK 4096                          // edges per block in hist/binfill
#define BHIST_NB ((N_EDGES + BINBLK - 1) / BINBLK)   // 391
#define PAD_NB ((N_NODES * 16 + 255) / 256)          // 3125

// ---------------- bf16 helpers ----------------
__device__ __forceinline__ float4 bf4_to_f4(uint2 v) {
    float4 r;
    r.x = __uint_as_float(v.x << 16);
    r.y = __uint_as_float(v.x & 0xffff0000u);
    r.z = __uint_as_float(v.y << 16);
    r.w = __uint_as_float(v.y & 0xffff0000u);
    return r;
}
__device__ __forceinline__ unsigned f2bf(float f) {
    unsigned u = __float_as_uint(f);
    return (u + 0x7fffu + ((u >> 16) & 1u)) >> 16;
}
__device__ __forceinline__ uint2 f4_to_bf4(float4 a) {
    uint2 v;
    v.x = f2bf(a.x) | (f2bf(a.y) << 16);
    v.y = f2bf(a.z) | (f2bf(a.w) << 16);
    return v;
}

// ---------------- block scan helper (256 threads, 4 waves) ----------------
__device__ __forceinline__ int block_excl_scan256(int v, int t) {
    __shared__ int ws[4];
    int lane = t & 63, w = t >> 6;
    int x = v;
    #pragma unroll
    for (int off = 1; off < 64; off <<= 1) {
        int y = __shfl_up(x, off, 64);
        if (lane >= off) x += y;
    }
    if (lane == 63) ws[w] = x;
    __syncthreads();
    int b0 = ws[0], b1 = ws[1], b2 = ws[2];
    int wbase = (w > 0 ? b0 : 0) + (w > 1 ? b1 : 0) + (w > 2 ? b2 : 0);
    return wbase + x - v;  // exclusive
}

// ---------------- bucket histogram + x16 pad (fused, block-range split) ------
__global__ __launch_bounds__(256) void k_bhist_pad(const int* __restrict__ dst,
                                                   int* __restrict__ bhist,
                                                   const float* __restrict__ x,
                                                   float* __restrict__ x16) {
    int bid = blockIdx.x;
    if (bid < BHIST_NB) {
        __shared__ int h[NBUCK];
        int t = threadIdx.x;
        h[t] = 0;
        __syncthreads();
        int base = bid * BINBLK;
        #pragma unroll
        for (int i = 0; i < 16; i++) {
            int e = base + i * 256 + t;
            if (e < N_EDGES) atomicAdd(&h[dst[e] >> BUCK_SHIFT], 1);
        }
        __syncthreads();
        if (h[t]) atomicAdd(&bhist[t], h[t]);
    } else {
        int idx = (bid - BHIST_NB) * 256 + threadIdx.x;
        if (idx < N_NODES * 16) {
            int n = idx >> 4, f = idx & 15;
            x16[idx] = (f < 9) ? x[n * 9 + f] : 0.f;
        }
    }
}

__global__ void k_bscan(const int* __restrict__ bhist, int* __restrict__ bstart,
                        int* __restrict__ bfill) {
    int t = threadIdx.x;
    int v = bhist[t];
    int ex = block_excl_scan256(v, t);
    bstart[t] = ex;
    bfill[t] = ex;
    if (t == 255) bstart[NBUCK] = ex + v;  // == N_EDGES
}

// bin edges into bucket regions of temp[]; payload packed 4B: (dst&255)<<16 | src
__global__ __launch_bounds__(256) void k_binfill(const int* __restrict__ src,
                                                 const int* __restrict__ dst,
                                                 int* __restrict__ bfill,
                                                 unsigned* __restrict__ temp) {
    __shared__ int h[NBUCK], gp[NBUCK], rk[NBUCK];
    int t = threadIdx.x;
    h[t] = 0; rk[t] = 0;
    __syncthreads();
    int base = blockIdx.x * BINBLK;
    int ss[16], dd[16];
    #pragma unroll
    for (int i = 0; i < 16; i++) {
        int e = base + i * 256 + t;
        bool ok = e < N_EDGES;
        ss[i] = ok ? src[e] : 0;
        dd[i] = ok ? dst[e] : -1;
        if (ok) atomicAdd(&h[dd[i] >> BUCK_SHIFT], 1);
    }
    __syncthreads();
    if (h[t]) gp[t] = atomicAdd(&bfill[t], h[t]);
    __syncthreads();
    #pragma unroll
    for (int i = 0; i < 16; i++) {
        if (dd[i] >= 0) {
            int b = dd[i] >> BUCK_SHIFT;
            int r = atomicAdd(&rk[b], 1);
            temp[gp[b] + r] = ((unsigned)(dd[i] & 255) << 16) | (unsigned)ss[i];
        }
    }
}

// one block per bucket: per-node counts/offsets/dis in LDS, then confined scatter
__global__ __launch_bounds__(256) void k_csrbuild(const unsigned* __restrict__ temp,
                                                  const int* __restrict__ bstart,
                                                  int* __restrict__ offs,
                                                  float* __restrict__ dis,
                                                  int* __restrict__ csr_src) {
    __shared__ int cnt[256], loff[256], rk[256];
    int b = blockIdx.x, t = threadIdx.x;
    int e0 = bstart[b], e1 = bstart[b + 1];
    int n0 = b << BUCK_SHIFT;
    cnt[t] = 0; rk[t] = 0;
    __syncthreads();
    for (int e = e0 + t; e < e1; e += 256)
        atomicAdd(&cnt[temp[e] >> 16], 1);
    __syncthreads();
    int c = cnt[t];
    int ex = block_excl_scan256(c, t);
    loff[t] = ex;
    int n = n0 + t;
    if (n < N_NODES) {
        offs[n] = e0 + ex;
        dis[n] = rsqrtf((float)c + 1.0f);
    }
    if (b == 0 && t == 0) offs[N_NODES] = N_EDGES;
    __syncthreads();
    for (int e = e0 + t; e < e1; e += 256) {
        unsigned v = temp[e];
        int li = v >> 16;
        int r = atomicAdd(&rk[li], 1);
        csr_src[e0 + loff[li] + r] = (int)(v & 0xffffu);
    }
}

// ---------------- layer 1 aggregation in 16-dim padded space ----------------
// y[n] = dn * sum_e dis_s*x16[src] + dn^2*x16[n]
__global__ __launch_bounds__(256) void k_agg9(const float* __restrict__ x16,
                                              const int* __restrict__ offs,
                                              const int* __restrict__ csr_src,
                                              const float* __restrict__ dis,
                                              float* __restrict__ y) {
    int wv = threadIdx.x >> 6, lane = threadIdx.x & 63;
    int n = blockIdx.x * 4 + wv;
    if (n >= N_NODES) return;
    int slot = lane >> 4, fl = lane & 15;
    int e0 = offs[n], e1 = offs[n + 1];
    float acc = 0.f;
    for (int e = e0 + slot; e < e1; e += 16) {
        int ss[4]; float cc[4];
        #pragma unroll
        for (int i = 0; i < 4; i++) {
            int ei = e + i * 4;
            bool ok = ei < e1;
            ss[i] = ok ? csr_src[ei] : n;
            cc[i] = ok ? dis[ss[i]] : 0.f;
        }
        #pragma unroll
        for (int i = 0; i < 4; i++)
            acc += cc[i] * x16[(size_t)ss[i] * 16 + fl];
    }
    acc += __shfl_xor(acc, 16, 64);
    acc += __shfl_xor(acc, 32, 64);
    float dn = dis[n];
    acc = dn * acc + dn * dn * x16[(size_t)n * 16 + fl];
    if (slot == 0) y[(size_t)n * 16 + fl] = acc;
}

// ---------------- fused layer1-gemm + relu + layer2-gemm ----------------
// out = bf16( relu(y16 @ W1 + b1) @ W2 ), linear [N][128] bf16
__global__ __launch_bounds__(256) void k_fused12(const float* __restrict__ y16,
                                                 const float* __restrict__ W1,
                                                 const float* __restrict__ b1,
                                                 const float* __restrict__ W2,
                                                 uint2* __restrict__ out8) {
    __shared__ float htile[64 * 128];
    __shared__ float ytile[64 * 16];
    int t = threadIdx.x;
    int n0 = blockIdx.x * 64;
    ((float4*)ytile)[t] = ((const float4*)(y16 + (size_t)n0 * 16))[t];
    __syncthreads();
    int q = t & 31;
    int tn = t >> 5;
    const float4* W14 = (const float4*)W1;
    float4 w1q[9];
    #pragma unroll
    for (int k = 0; k < 9; k++) w1q[k] = W14[k * 32 + q];
    float4 bq = ((const float4*)b1)[q];
    #pragma unroll
    for (int r = 0; r < 8; r++) {
        int row = tn * 8 + r;
        float4 a = bq;
        #pragma unroll
        for (int k = 0; k < 9; k++) {
            float yv = ytile[row * 16 + k];
            a.x += yv * w1q[k].x; a.y += yv * w1q[k].y;
            a.z += yv * w1q[k].z; a.w += yv * w1q[k].w;
        }
        *(float4*)&htile[row * 128 + 4 * q] =
            make_float4(fmaxf(a.x, 0.f), fmaxf(a.y, 0.f),
                        fmaxf(a.z, 0.f), fmaxf(a.w, 0.f));
    }
    __syncthreads();
    float4 acc[8];
    #pragma unroll
    for (int r = 0; r < 8; r++) acc[r] = make_float4(0.f, 0.f, 0.f, 0.f);
    const float4* W4 = (const float4*)W2;
    for (int k = 0; k < 128; k += 2) {
        float4 w0 = W4[k * 32 + q];
        float4 w1 = W4[(k + 1) * 32 + q];
        #pragma unroll
        for (int r = 0; r < 8; r++) {
            int row = tn * 8 + r;
            float2 hk = *(const float2*)&htile[row * 128 + k];
            acc[r].x += hk.x * w0.x; acc[r].y += hk.x * w0.y;
            acc[r].z += hk.x * w0.z; acc[r].w += hk.x * w0.w;
            acc[r].x += hk.y * w1.x; acc[r].y += hk.y * w1.y;
            acc[r].z += hk.y * w1.z; acc[r].w += hk.y * w1.w;
        }
    }
    #pragma unroll
    for (int r = 0; r < 8; r++) {
        int n = n0 + tn * 8 + r;
        if (n < N_NODES) out8[(size_t)n * 32 + q] = f4_to_bf4(acc[r]);
    }
}

// ---------------- bf16 gather-agg (layer 2), 32 edges/iter deep-MLP ----------
// wave-per-node: lane = 4 bf16 (8B), 32 lanes/row, 2 edges per load slot,
// 32 rows in flight; no min-wave bound so VGPR can float (no spill)
__global__ __launch_bounds__(256) void k_agg2(const uint2* __restrict__ h8,
                                              const int* __restrict__ offs,
                                              const int* __restrict__ csr_src,
                                              const float* __restrict__ dis,
                                              const float* __restrict__ bias,
                                              uint2* __restrict__ out) {
    int wv = threadIdx.x >> 6, lane = threadIdx.x & 63;
    int n = blockIdx.x * 4 + wv;
    if (n >= N_NODES) return;
    int half = lane >> 5;
    int fl = lane & 31;
    int e0 = offs[n], e1 = offs[n + 1];
    float4 acc = make_float4(0.f, 0.f, 0.f, 0.f);
    for (int e = e0 + half; e < e1; e += 32) {
        int ss[16]; float cc[16];
        #pragma unroll
        for (int i = 0; i < 16; i++) {
            int ei = e + i * 2;
            bool ok = ei < e1;
            ss[i] = ok ? csr_src[ei] : n;
            cc[i] = ok ? dis[ss[i]] : 0.f;
        }
        uint2 rows[16];
        #pragma unroll
        for (int i = 0; i < 16; i++)
            rows[i] = h8[(size_t)ss[i] * 32 + fl];
        #pragma unroll
        for (int i = 0; i < 16; i++) {
            float4 r = bf4_to_f4(rows[i]);
            acc.x += cc[i] * r.x;
            acc.y += cc[i] * r.y;
            acc.z += cc[i] * r.z;
            acc.w += cc[i] * r.w;
        }
    }
    acc.x += __shfl_xor(acc.x, 32, 64);
    acc.y += __shfl_xor(acc.y, 32, 64);
    acc.z += __shfl_xor(acc.z, 32, 64);
    acc.w += __shfl_xor(acc.w, 32, 64);
    float dn = dis[n];
    float4 hv = bf4_to_f4(h8[(size_t)n * 32 + fl]);
    acc.x = dn * acc.x + dn * dn * hv.x + bias[4 * fl];
    acc.y = dn * acc.y + dn * dn * hv.y + bias[4 * fl + 1];
    acc.z = dn * acc.z + dn * dn * hv.z + bias[4 * fl + 2];
    acc.w = dn * acc.w + dn * dn * hv.w + bias[4 * fl + 3];
    acc.x = fmaxf(acc.x, 0.f);
    acc.y = fmaxf(acc.y, 0.f);
    acc.z = fmaxf(acc.z, 0.f);
    acc.w = fmaxf(acc.w, 0.f);
    if (half == 0) out[(size_t)n * 32 + fl] = f4_to_bf4(acc);
}

// ---------------- layer-3 agg fused with mean-pool accumulation --------------
__global__ __launch_bounds__(256) void k_aggp(const uint2* __restrict__ h8,
                                              const int* __restrict__ offs,
                                              const int* __restrict__ csr_src,
                                              const float* __restrict__ dis,
                                              const int* __restrict__ batch,
                                              float* __restrict__ sums) {
    __shared__ float red[4][128];
    __shared__ int gid[4];
    int wv = threadIdx.x >> 6, lane = threadIdx.x & 63;
    int n = blockIdx.x * 4 + wv;     // N_NODES == 12500*4, no tail
    int half = lane >> 5;
    int fl = lane & 31;
    int e0 = offs[n], e1 = offs[n + 1];
    float4 acc = make_float4(0.f, 0.f, 0.f, 0.f);
    for (int e = e0 + half; e < e1; e += 32) {
        int ss[16]; float cc[16];
        #pragma unroll
        for (int i = 0; i < 16; i++) {
            int ei = e + i * 2;
            bool ok = ei < e1;
            ss[i] = ok ? csr_src[ei] : n;
            cc[i] = ok ? dis[ss[i]] : 0.f;
        }
        uint2 rows[16];
        #pragma unroll
        for (int i = 0; i < 16; i++)
            rows[i] = h8[(size_t)ss[i] * 32 + fl];
        #pragma unroll
        for (int i = 0; i < 16; i++) {
            float4 r = bf4_to_f4(rows[i]);
            acc.x += cc[i] * r.x;
            acc.y += cc[i] * r.y;
            acc.z += cc[i] * r.z;
            acc.w += cc[i] * r.w;
        }
    }
    acc.x += __shfl_xor(acc.x, 32, 64);
    acc.y += __shfl_xor(acc.y, 32, 64);
    acc.z += __shfl_xor(acc.z, 32, 64);
    acc.w += __shfl_xor(acc.w, 32, 64);
    float dn = dis[n];
    float4 hv = bf4_to_f4(h8[(size_t)n * 32 + fl]);
    acc.x = dn * acc.x + dn * dn * hv.x;
    acc.y = dn * acc.y + dn * dn * hv.y;
    acc.z = dn * acc.z + dn * dn * hv.z;
    acc.w = dn * acc.w + dn * dn * hv.w;
    if (half == 0) *(float4*)&red[wv][4 * fl] = acc;
    if (lane == 0) gid[wv] = batch[n];
    __syncthreads();
    int t = threadIdx.x;
    if (t < 128) {
        int g0 = gid[0], g1 = gid[1], g2 = gid[2], g3 = gid[3];
        float v0 = red[0][t], v1 = red[1][t], v2 = red[2][t], v3 = red[3][t];
        if (g0 == g3) {  // sorted batch -> all four equal
            atomicAdd(&sums[g0 * 128 + t], v0 + v1 + v2 + v3);
        } else {
            atomicAdd(&sums[g0 * 128 + t], v0);
            atomicAdd(&sums[g1 * 128 + t], v1);
            atomicAdd(&sums[g2 * 128 + t], v2);
            atomicAdd(&sums[g3 * 128 + t], v3);
        }
    }
}

// ---------------- final: counts via binary search + tiny GEMM ----------------
__global__ void k_final(const float* __restrict__ sums, const int* __restrict__ batch,
                        const float* __restrict__ W3, const float* __restrict__ b3,
                        float* __restrict__ out) {
    int idx = blockIdx.x * blockDim.x + threadIdx.x;
    if (idx >= N_GRAPHS * HID) return;
    int g = idx >> 7, j = idx & 127;
    int lo = 0, hi = N_NODES;
    while (lo < hi) { int m = (lo + hi) >> 1; if (batch[m] <= g) lo = m + 1; else hi = m; }
    int ub_g = lo;
    lo = 0; hi = N_NODES;
    int gm1 = g - 1;
    while (lo < hi) { int m = (lo + hi) >> 1; if (batch[m] <= gm1) lo = m + 1; else hi = m; }
    int cnt = ub_g - lo;
    float inv = 1.0f / fmaxf((float)cnt, 1.0f);
    const float* srow = sums + g * 128;
    float acc = 0.f;
    for (int k = 0; k < 128; k++) acc += srow[k] * W3[k * 128 + j];
    out[idx] = acc * inv + b3[j];
}

extern "C" void kernel_launch(void* const* d_in, const int* in_sizes, int n_in,
                              void* d_out, int out_size, void* d_ws, size_t ws_size,
                              hipStream_t stream) {
    const float* x     = (const float*)d_in[0];
    const int*   ei    = (const int*)d_in[1];
    const int*   batch = (const int*)d_in[2];
    const float* W1    = (const float*)d_in[3];
    const float* b1    = (const float*)d_in[4];
    const float* W2    = (const float*)d_in[5];
    const float* b2    = (const float*)d_in[6];
    const float* W3    = (const float*)d_in[7];
    const float* b3    = (const float*)d_in[8];
    float* out = (float*)d_out;
    const int* src = ei;
    const int* dst = ei + N_EDGES;

    char* ws = (char*)d_ws;
    size_t off = 0;
    auto alloc = [&](size_t bytes) -> void* {
        void* p = ws + off;
        off += (bytes + 255) & ~(size_t)255;
        return p;
    };
    int*      bhist   = (int*)alloc((size_t)NBUCK * 4);              // | adjacent:
    float*    sums    = (float*)alloc((size_t)N_GRAPHS * 128 * 4);   // | one memset
    unsigned* hb1     = (unsigned*)alloc((size_t)N_NODES * 64 * 4);  // bf16 [N][128]
    unsigned* hb2     = (unsigned*)alloc((size_t)N_NODES * 64 * 4);  // bf16 [N][128]
    unsigned* temp    = (unsigned*)alloc((size_t)N_EDGES * 4);       // packed (ldst<<16|src)
    int*      csr_src = (int*)alloc((size_t)N_EDGES * 4);
    int*      bstart  = (int*)alloc((size_t)(NBUCK + 1) * 4);
    int*      bfill   = (int*)alloc((size_t)NBUCK * 4);
    int*      offs    = (int*)alloc((size_t)(N_NODES + 1) * 4);
    float*    dis     = (float*)alloc((size_t)N_NODES * 4);
    float*    x16     = (float*)alloc((size_t)N_NODES * 16 * 4);
    float*    y16     = (float*)alloc((size_t)(N_NODES + 64) * 16 * 4);  // +pad for tile overread

    // bhist (1KB, 256-aligned) and sums (128KB) are adjacent -> single memset
    hipMemsetAsync(bhist, 0, (size_t)NBUCK * 4 + (size_t)N_GRAPHS * 128 * 4, stream);

    k_bhist_pad<<<BHIST_NB + PAD_NB, 256, 0, stream>>>(dst, bhist, x, x16);
    k_bscan<<<1, 256, 0, stream>>>(bhist, bstart, bfill);
    k_binfill<<<BHIST_NB, 256, 0, stream>>>(src, dst, bfill, temp);
    k_csrbuild<<<NBUCK_USED, 256, 0, stream>>>(temp, bstart, offs, dis, csr_src);

    // layer 1 aggregate in 9-dim space, then fused GEMMs -> hb1 = bf16(relu(y@W1+b1)@W2)
    k_agg9<<<(N_NODES + 3) / 4, 256, 0, stream>>>(x16, offs, csr_src, dis, y16);
    k_fused12<<<(N_NODES + 63) / 64, 256, 0, stream>>>(y16, W1, b1, W2, (uint2*)hb1);
    // layer 2 agg: hb2 = bf16(relu(agg(hb1) + b2))
    k_agg2<<<N_NODES / 4, 256, 0, stream>>>((const uint2*)hb1, offs, csr_src, dis,
                                            b2, (uint2*)hb2);
    // layer 3 agg fused with pooling (W3 deferred): sums += per-graph agg rows
    k_aggp<<<N_NODES / 4, 256, 0, stream>>>((const uint2*)hb2, offs, csr_src, dis,
                                            batch, sums);
    // final tiny GEMM with inline counts
    k_final<<<(N_GRAPHS * HID + 255) / 256, 256, 0, stream>>>(sums, batch, W3, b3, out);
}

// Round 12
// 295.601 us; speedup vs baseline: 1.0900x; 1.0900x over previous
//
#include <hip/hip_runtime.h>

#define N_NODES 50000
#define N_EDGES 1600000
#define N_GRAPHS 256
#define HID 128

#define NBUCK 256
#define BUCK_SHIFT 8
#define NBUCK_USED ((N_NODES + 255) >> 8)   // 196
#define BINBLK 4096                          // edges per block in hist/binfill
#define BHIST_NB ((N_EDGES + BINBLK - 1) / BINBLK)   // 391
#define PAD_NB ((N_NODES * 16 + 255) / 256)          // 3125

typedef unsigned uvec4 __attribute__((ext_vector_type(4)));

// ---------------- bf16 helpers ----------------
__device__ __forceinline__ float4 bf4_to_f4(unsigned lo, unsigned hi) {
    float4 r;
    r.x = __uint_as_float(lo << 16);
    r.y = __uint_as_float(lo & 0xffff0000u);
    r.z = __uint_as_float(hi << 16);
    r.w = __uint_as_float(hi & 0xffff0000u);
    return r;
}
__device__ __forceinline__ unsigned f2bf(float f) {
    unsigned u = __float_as_uint(f);
    return (u + 0x7fffu + ((u >> 16) & 1u)) >> 16;
}
__device__ __forceinline__ uint2 f4_to_bf4(float4 a) {
    uint2 v;
    v.x = f2bf(a.x) | (f2bf(a.y) << 16);
    v.y = f2bf(a.z) | (f2bf(a.w) << 16);
    return v;
}

// ---------------- block scan helper (256 threads, 4 waves) ----------------
__device__ __forceinline__ int block_excl_scan256(int v, int t) {
    __shared__ int ws[4];
    int lane = t & 63, w = t >> 6;
    int x = v;
    #pragma unroll
    for (int off = 1; off < 64; off <<= 1) {
        int y = __shfl_up(x, off, 64);
        if (lane >= off) x += y;
    }
    if (lane == 63) ws[w] = x;
    __syncthreads();
    int b0 = ws[0], b1 = ws[1], b2 = ws[2];
    int wbase = (w > 0 ? b0 : 0) + (w > 1 ? b1 : 0) + (w > 2 ? b2 : 0);
    return wbase + x - v;  // exclusive
}

// ---------------- bucket histogram + x16 pad (fused, block-range split) ------
__global__ __launch_bounds__(256) void k_bhist_pad(const int* __restrict__ dst,
                                                   int* __restrict__ bhist,
                                                   const float* __restrict__ x,
                                                   float* __restrict__ x16) {
    int bid = blockIdx.x;
    if (bid < BHIST_NB) {
        __shared__ int h[NBUCK];
        int t = threadIdx.x;
        h[t] = 0;
        __syncthreads();
        int base = bid * BINBLK;
        #pragma unroll
        for (int i = 0; i < 16; i++) {
            int e = base + i * 256 + t;
            if (e < N_EDGES) atomicAdd(&h[dst[e] >> BUCK_SHIFT], 1);
        }
        __syncthreads();
        if (h[t]) atomicAdd(&bhist[t], h[t]);
    } else {
        int idx = (bid - BHIST_NB) * 256 + threadIdx.x;
        if (idx < N_NODES * 16) {
            int n = idx >> 4, f = idx & 15;
            x16[idx] = (f < 9) ? x[n * 9 + f] : 0.f;
        }
    }
}

__global__ void k_bscan(const int* __restrict__ bhist, int* __restrict__ bstart,
                        int* __restrict__ bfill) {
    int t = threadIdx.x;
    int v = bhist[t];
    int ex = block_excl_scan256(v, t);
    bstart[t] = ex;
    bfill[t] = ex;
    if (t == 255) bstart[NBUCK] = ex + v;  // == N_EDGES
}

// bin edges into bucket regions of temp[]; payload packed 4B: (dst&255)<<16 | src
__global__ __launch_bounds__(256) void k_binfill(const int* __restrict__ src,
                                                 const int* __restrict__ dst,
                                                 int* __restrict__ bfill,
                                                 unsigned* __restrict__ temp) {
    __shared__ int h[NBUCK], gp[NBUCK], rk[NBUCK];
    int t = threadIdx.x;
    h[t] = 0; rk[t] = 0;
    __syncthreads();
    int base = blockIdx.x * BINBLK;
    int ss[16], dd[16];
    #pragma unroll
    for (int i = 0; i < 16; i++) {
        int e = base + i * 256 + t;
        bool ok = e < N_EDGES;
        ss[i] = ok ? src[e] : 0;
        dd[i] = ok ? dst[e] : -1;
        if (ok) atomicAdd(&h[dd[i] >> BUCK_SHIFT], 1);
    }
    __syncthreads();
    if (h[t]) gp[t] = atomicAdd(&bfill[t], h[t]);
    __syncthreads();
    #pragma unroll
    for (int i = 0; i < 16; i++) {
        if (dd[i] >= 0) {
            int b = dd[i] >> BUCK_SHIFT;
            int r = atomicAdd(&rk[b], 1);
            temp[gp[b] + r] = ((unsigned)(dd[i] & 255) << 16) | (unsigned)ss[i];
        }
    }
}

// one block per bucket: per-node counts/offsets/dis in LDS, then confined scatter
__global__ __launch_bounds__(256) void k_csrbuild(const unsigned* __restrict__ temp,
                                                  const int* __restrict__ bstart,
                                                  int* __restrict__ offs,
                                                  float* __restrict__ dis,
                                                  int* __restrict__ csr_src) {
    __shared__ int cnt[256], loff[256], rk[256];
    int b = blockIdx.x, t = threadIdx.x;
    int e0 = bstart[b], e1 = bstart[b + 1];
    int n0 = b << BUCK_SHIFT;
    cnt[t] = 0; rk[t] = 0;
    __syncthreads();
    for (int e = e0 + t; e < e1; e += 256)
        atomicAdd(&cnt[temp[e] >> 16], 1);
    __syncthreads();
    int c = cnt[t];
    int ex = block_excl_scan256(c, t);
    loff[t] = ex;
    int n = n0 + t;
    if (n < N_NODES) {
        offs[n] = e0 + ex;
        dis[n] = rsqrtf((float)c + 1.0f);
    }
    if (b == 0 && t == 0) offs[N_NODES] = N_EDGES;
    __syncthreads();
    for (int e = e0 + t; e < e1; e += 256) {
        unsigned v = temp[e];
        int li = v >> 16;
        int r = atomicAdd(&rk[li], 1);
        csr_src[e0 + loff[li] + r] = (int)(v & 0xffffu);
    }
}

// ---------------- layer 1 aggregation in 16-dim padded space ----------------
// y[n] = dn * sum_e dis_s*x16[src] + dn^2*x16[n]
__global__ __launch_bounds__(256) void k_agg9(const float* __restrict__ x16,
                                              const int* __restrict__ offs,
                                              const int* __restrict__ csr_src,
                                              const float* __restrict__ dis,
                                              float* __restrict__ y) {
    int wv = threadIdx.x >> 6, lane = threadIdx.x & 63;
    int n = blockIdx.x * 4 + wv;
    if (n >= N_NODES) return;
    int slot = lane >> 4, fl = lane & 15;
    int e0 = offs[n], e1 = offs[n + 1];
    float acc = 0.f;
    for (int e = e0 + slot; e < e1; e += 16) {
        int ss[4]; float cc[4];
        #pragma unroll
        for (int i = 0; i < 4; i++) {
            int ei = e + i * 4;
            bool ok = ei < e1;
            ss[i] = ok ? csr_src[ei] : n;
            cc[i] = ok ? dis[ss[i]] : 0.f;
        }
        #pragma unroll
        for (int i = 0; i < 4; i++)
            acc += cc[i] * x16[(size_t)ss[i] * 16 + fl];
    }
    acc += __shfl_xor(acc, 16, 64);
    acc += __shfl_xor(acc, 32, 64);
    float dn = dis[n];
    acc = dn * acc + dn * dn * x16[(size_t)n * 16 + fl];
    if (slot == 0) y[(size_t)n * 16 + fl] = acc;
}

// ---------------- fused layer1-gemm + relu + layer2-gemm ----------------
// out = bf16( relu(y16 @ W1 + b1) @ W2 ), linear [N][128] bf16
__global__ __launch_bounds__(256) void k_fused12(const float* __restrict__ y16,
                                                 const float* __restrict__ W1,
                                                 const float* __restrict__ b1,
                                                 const float* __restrict__ W2,
                                                 uint2* __restrict__ out8) {
    __shared__ float htile[64 * 128];
    __shared__ float ytile[64 * 16];
    int t = threadIdx.x;
    int n0 = blockIdx.x * 64;
    ((float4*)ytile)[t] = ((const float4*)(y16 + (size_t)n0 * 16))[t];
    __syncthreads();
    int q = t & 31;
    int tn = t >> 5;
    const float4* W14 = (const float4*)W1;
    float4 w1q[9];
    #pragma unroll
    for (int k = 0; k < 9; k++) w1q[k] = W14[k * 32 + q];
    float4 bq = ((const float4*)b1)[q];
    #pragma unroll
    for (int r = 0; r < 8; r++) {
        int row = tn * 8 + r;
        float4 a = bq;
        #pragma unroll
        for (int k = 0; k < 9; k++) {
            float yv = ytile[row * 16 + k];
            a.x += yv * w1q[k].x; a.y += yv * w1q[k].y;
            a.z += yv * w1q[k].z; a.w += yv * w1q[k].w;
        }
        *(float4*)&htile[row * 128 + 4 * q] =
            make_float4(fmaxf(a.x, 0.f), fmaxf(a.y, 0.f),
                        fmaxf(a.z, 0.f), fmaxf(a.w, 0.f));
    }
    __syncthreads();
    float4 acc[8];
    #pragma unroll
    for (int r = 0; r < 8; r++) acc[r] = make_float4(0.f, 0.f, 0.f, 0.f);
    const float4* W4 = (const float4*)W2;
    for (int k = 0; k < 128; k += 2) {
        float4 w0 = W4[k * 32 + q];
        float4 w1 = W4[(k + 1) * 32 + q];
        #pragma unroll
        for (int r = 0; r < 8; r++) {
            int row = tn * 8 + r;
            float2 hk = *(const float2*)&htile[row * 128 + k];
            acc[r].x += hk.x * w0.x; acc[r].y += hk.x * w0.y;
            acc[r].z += hk.x * w0.z; acc[r].w += hk.x * w0.w;
            acc[r].x += hk.y * w1.x; acc[r].y += hk.y * w1.y;
            acc[r].z += hk.y * w1.z; acc[r].w += hk.y * w1.w;
        }
    }
    #pragma unroll
    for (int r = 0; r < 8; r++) {
        int n = n0 + tn * 8 + r;
        if (n < N_NODES) out8[(size_t)n * 32 + q] = f4_to_bf4(acc[r]);
    }
}

// ---------------- bf16 gather-agg, uint4 lanes (16B), 16 lanes/row -----------
// 4 edge-slots x 16 lanes; one row-load instruction gathers 4 rows (vs 2 before)
// -> half the VMEM instructions at the same line count. 16 edges per iteration.
template <int POOL>
__global__ __launch_bounds__(256) void k_agg16(const uvec4* __restrict__ h16,
                                               const int* __restrict__ offs,
                                               const int* __restrict__ csr_src,
                                               const float* __restrict__ dis,
                                               const float* __restrict__ bias,
                                               uint2* __restrict__ out,
                                               const int* __restrict__ batch,
                                               float* __restrict__ sums) {
    __shared__ float red[4][128];
    __shared__ int gid[4];
    int wv = threadIdx.x >> 6, lane = threadIdx.x & 63;
    int n = blockIdx.x * 4 + wv;     // N_NODES == 12500*4, no tail
    int slot = lane >> 4;            // edge slot 0..3
    int fl = lane & 15;              // 16B granule within 256B row (8 bf16)
    int e0 = offs[n], e1 = offs[n + 1];
    float4 aLo = make_float4(0.f, 0.f, 0.f, 0.f);
    float4 aHi = make_float4(0.f, 0.f, 0.f, 0.f);
    for (int e = e0 + slot; e < e1; e += 16) {
        int ss[4]; float cc[4];
        #pragma unroll
        for (int i = 0; i < 4; i++) {
            int ei = e + i * 4;
            bool ok = ei < e1;
            ss[i] = ok ? csr_src[ei] : n;
            cc[i] = ok ? dis[ss[i]] : 0.f;
        }
        uvec4 rows[4];
        #pragma unroll
        for (int i = 0; i < 4; i++)
            rows[i] = __builtin_nontemporal_load(&h16[(size_t)ss[i] * 16 + fl]);
        #pragma unroll
        for (int i = 0; i < 4; i++) {
            float4 rl = bf4_to_f4(rows[i].x, rows[i].y);
            float4 rh = bf4_to_f4(rows[i].z, rows[i].w);
            aLo.x += cc[i] * rl.x; aLo.y += cc[i] * rl.y;
            aLo.z += cc[i] * rl.z; aLo.w += cc[i] * rl.w;
            aHi.x += cc[i] * rh.x; aHi.y += cc[i] * rh.y;
            aHi.z += cc[i] * rh.z; aHi.w += cc[i] * rh.w;
        }
    }
    // butterfly over the 4 slots (lanes fl, fl+16, fl+32, fl+48)
    #pragma unroll
    for (int off = 16; off < 64; off <<= 1) {
        aLo.x += __shfl_xor(aLo.x, off, 64);
        aLo.y += __shfl_xor(aLo.y, off, 64);
        aLo.z += __shfl_xor(aLo.z, off, 64);
        aLo.w += __shfl_xor(aLo.w, off, 64);
        aHi.x += __shfl_xor(aHi.x, off, 64);
        aHi.y += __shfl_xor(aHi.y, off, 64);
        aHi.z += __shfl_xor(aHi.z, off, 64);
        aHi.w += __shfl_xor(aHi.w, off, 64);
    }
    float dn = dis[n];
    uvec4 hvv = h16[(size_t)n * 16 + fl];
    float4 hLo = bf4_to_f4(hvv.x, hvv.y);
    float4 hHi = bf4_to_f4(hvv.z, hvv.w);
    aLo.x = dn * aLo.x + dn * dn * hLo.x;
    aLo.y = dn * aLo.y + dn * dn * hLo.y;
    aLo.z = dn * aLo.z + dn * dn * hLo.z;
    aLo.w = dn * aLo.w + dn * dn * hLo.w;
    aHi.x = dn * aHi.x + dn * dn * hHi.x;
    aHi.y = dn * aHi.y + dn * dn * hHi.y;
    aHi.z = dn * aHi.z + dn * dn * hHi.z;
    aHi.w = dn * aHi.w + dn * dn * hHi.w;
    if (!POOL) {
        float4 b0 = ((const float4*)bias)[2 * fl];
        float4 b1v = ((const float4*)bias)[2 * fl + 1];
        aLo.x = fmaxf(aLo.x + b0.x, 0.f);
        aLo.y = fmaxf(aLo.y + b0.y, 0.f);
        aLo.z = fmaxf(aLo.z + b0.z, 0.f);
        aLo.w = fmaxf(aLo.w + b0.w, 0.f);
        aHi.x = fmaxf(aHi.x + b1v.x, 0.f);
        aHi.y = fmaxf(aHi.y + b1v.y, 0.f);
        aHi.z = fmaxf(aHi.z + b1v.z, 0.f);
        aHi.w = fmaxf(aHi.w + b1v.w, 0.f);
        if (slot == 0) {
            uint2 lo = f4_to_bf4(aLo), hi = f4_to_bf4(aHi);
            uvec4 o; o.x = lo.x; o.y = lo.y; o.z = hi.x; o.w = hi.y;
            ((uvec4*)out)[(size_t)n * 16 + fl] = o;
        }
    } else {
        if (slot == 0) {
            *(float4*)&red[wv][8 * fl] = aLo;
            *(float4*)&red[wv][8 * fl + 4] = aHi;
        }
        if (lane == 0) gid[wv] = batch[n];
        __syncthreads();
        int t = threadIdx.x;
        if (t < 128) {
            int g0 = gid[0], g1 = gid[1], g2 = gid[2], g3 = gid[3];
            float v0 = red[0][t], v1 = red[1][t], v2 = red[2][t], v3 = red[3][t];
            if (g0 == g3) {  // sorted batch -> all four equal
                atomicAdd(&sums[g0 * 128 + t], v0 + v1 + v2 + v3);
            } else {
                atomicAdd(&sums[g0 * 128 + t], v0);
                atomicAdd(&sums[g1 * 128 + t], v1);
                atomicAdd(&sums[g2 * 128 + t], v2);
                atomicAdd(&sums[g3 * 128 + t], v3);
            }
        }
    }
}

// ---------------- final: counts via binary search + tiny GEMM ----------------
__global__ void k_final(const float* __restrict__ sums, const int* __restrict__ batch,
                        const float* __restrict__ W3, const float* __restrict__ b3,
                        float* __restrict__ out) {
    int idx = blockIdx.x * blockDim.x + threadIdx.x;
    if (idx >= N_GRAPHS * HID) return;
    int g = idx >> 7, j = idx & 127;
    int lo = 0, hi = N_NODES;
    while (lo < hi) { int m = (lo + hi) >> 1; if (batch[m] <= g) lo = m + 1; else hi = m; }
    int ub_g = lo;
    lo = 0; hi = N_NODES;
    int gm1 = g - 1;
    while (lo < hi) { int m = (lo + hi) >> 1; if (batch[m] <= gm1) lo = m + 1; else hi = m; }
    int cnt = ub_g - lo;
    float inv = 1.0f / fmaxf((float)cnt, 1.0f);
    const float* srow = sums + g * 128;
    float acc = 0.f;
    for (int k = 0; k < 128; k++) acc += srow[k] * W3[k * 128 + j];
    out[idx] = acc * inv + b3[j];
}

extern "C" void kernel_launch(void* const* d_in, const int* in_sizes, int n_in,
                              void* d_out, int out_size, void* d_ws, size_t ws_size,
                              hipStream_t stream) {
    const float* x     = (const float*)d_in[0];
    const int*   ei    = (const int*)d_in[1];
    const int*   batch = (const int*)d_in[2];
    const float* W1    = (const float*)d_in[3];
    const float* b1    = (const float*)d_in[4];
    const float* W2    = (const float*)d_in[5];
    const float* b2    = (const float*)d_in[6];
    const float* W3    = (const float*)d_in[7];
    const float* b3    = (const float*)d_in[8];
    float* out = (float*)d_out;
    const int* src = ei;
    const int* dst = ei + N_EDGES;

    char* ws = (char*)d_ws;
    size_t off = 0;
    auto alloc = [&](size_t bytes) -> void* {
        void* p = ws + off;
        off += (bytes + 255) & ~(size_t)255;
        return p;
    };
    int*      bhist   = (int*)alloc((size_t)NBUCK * 4);              // | adjacent:
    float*    sums    = (float*)alloc((size_t)N_GRAPHS * 128 * 4);   // | one memset
    unsigned* hb1     = (unsigned*)alloc((size_t)N_NODES * 64 * 4);  // bf16 [N][128]
    unsigned* hb2     = (unsigned*)alloc((size_t)N_NODES * 64 * 4);  // bf16 [N][128]
    unsigned* temp    = (unsigned*)alloc((size_t)N_EDGES * 4);       // packed (ldst<<16|src)
    int*      csr_src = (int*)alloc((size_t)N_EDGES * 4);
    int*      bstart  = (int*)alloc((size_t)(NBUCK + 1) * 4);
    int*      bfill   = (int*)alloc((size_t)NBUCK * 4);
    int*      offs    = (int*)alloc((size_t)(N_NODES + 1) * 4);
    float*    dis     = (float*)alloc((size_t)N_NODES * 4);
    float*    x16     = (float*)alloc((size_t)N_NODES * 16 * 4);
    float*    y16     = (float*)alloc((size_t)(N_NODES + 64) * 16 * 4);  // +pad for tile overread

    // bhist (1KB, 256-aligned) and sums (128KB) are adjacent -> single memset
    hipMemsetAsync(bhist, 0, (size_t)NBUCK * 4 + (size_t)N_GRAPHS * 128 * 4, stream);

    k_bhist_pad<<<BHIST_NB + PAD_NB, 256, 0, stream>>>(dst, bhist, x, x16);
    k_bscan<<<1, 256, 0, stream>>>(bhist, bstart, bfill);
    k_binfill<<<BHIST_NB, 256, 0, stream>>>(src, dst, bfill, temp);
    k_csrbuild<<<NBUCK_USED, 256, 0, stream>>>(temp, bstart, offs, dis, csr_src);

    // layer 1 aggregate in 9-dim space, then fused GEMMs -> hb1 = bf16(relu(y@W1+b1)@W2)
    k_agg9<<<(N_NODES + 3) / 4, 256, 0, stream>>>(x16, offs, csr_src, dis, y16);
    k_fused12<<<(N_NODES + 63) / 64, 256, 0, stream>>>(y16, W1, b1, W2, (uint2*)hb1);
    // layer 2 agg: hb2 = bf16(relu(agg(hb1) + b2))
    k_agg16<0><<<N_NODES / 4, 256, 0, stream>>>((const uvec4*)hb1, offs, csr_src, dis,
                                                b2, (uint2*)hb2, nullptr, nullptr);
    // layer 3 agg fused with pooling (W3 deferred): sums += per-graph agg rows
    k_agg16<1><<<N_NODES / 4, 256, 0, stream>>>((const uvec4*)hb2, offs, csr_src, dis,
                                                nullptr, nullptr, batch, sums);
    // final tiny GEMM with inline counts
    k_final<<<(N_GRAPHS * HID + 255) / 256, 256, 0, stream>>>(sums, batch, W3, b3, out);
}

// Round 13
// 274.697 us; speedup vs baseline: 1.1729x; 1.0761x over previous
//
#include <hip/hip_runtime.h>

#define N_NODES 50000
#define N_EDGES 1600000
#define N_GRAPHS 256
#define HID 128

#define NBUCK 256
#define BUCK_SHIFT 8
#define NBUCK_USED ((N_NODES + 255) >> 8)   // 196
#define BINBLK 4096                          // edges per block in hist/binfill
#define BHIST_NB ((N_EDGES + BINBLK - 1) / BINBLK)   // 391
#define PAD_NB ((N_NODES * 16 + 255) / 256)          // 3125

// ---------------- bf16 helpers ----------------
__device__ __forceinline__ float4 bf4_to_f4(uint2 v) {
    float4 r;
    r.x = __uint_as_float(v.x << 16);
    r.y = __uint_as_float(v.x & 0xffff0000u);
    r.z = __uint_as_float(v.y << 16);
    r.w = __uint_as_float(v.y & 0xffff0000u);
    return r;
}
__device__ __forceinline__ unsigned f2bf(float f) {
    unsigned u = __float_as_uint(f);
    return (u + 0x7fffu + ((u >> 16) & 1u)) >> 16;
}
__device__ __forceinline__ uint2 f4_to_bf4(float4 a) {
    uint2 v;
    v.x = f2bf(a.x) | (f2bf(a.y) << 16);
    v.y = f2bf(a.z) | (f2bf(a.w) << 16);
    return v;
}

// ---------------- block scan helper (256 threads, 4 waves) ----------------
__device__ __forceinline__ int block_excl_scan256(int v, int t) {
    __shared__ int ws[4];
    int lane = t & 63, w = t >> 6;
    int x = v;
    #pragma unroll
    for (int off = 1; off < 64; off <<= 1) {
        int y = __shfl_up(x, off, 64);
        if (lane >= off) x += y;
    }
    if (lane == 63) ws[w] = x;
    __syncthreads();
    int b0 = ws[0], b1 = ws[1], b2 = ws[2];
    int wbase = (w > 0 ? b0 : 0) + (w > 1 ? b1 : 0) + (w > 2 ? b2 : 0);
    return wbase + x - v;  // exclusive
}

// ---------------- bucket histogram + x16 pad (fused, block-range split) ------
__global__ __launch_bounds__(256) void k_bhist_pad(const int* __restrict__ dst,
                                                   int* __restrict__ bhist,
                                                   const float* __restrict__ x,
                                                   float* __restrict__ x16) {
    int bid = blockIdx.x;
    if (bid < BHIST_NB) {
        __shared__ int h[NBUCK];
        int t = threadIdx.x;
        h[t] = 0;
        __syncthreads();
        int base = bid * BINBLK;
        #pragma unroll
        for (int i = 0; i < 16; i++) {
            int e = base + i * 256 + t;
            if (e < N_EDGES) atomicAdd(&h[dst[e] >> BUCK_SHIFT], 1);
        }
        __syncthreads();
        if (h[t]) atomicAdd(&bhist[t], h[t]);
    } else {
        int idx = (bid - BHIST_NB) * 256 + threadIdx.x;
        if (idx < N_NODES * 16) {
            int n = idx >> 4, f = idx & 15;
            x16[idx] = (f < 9) ? x[n * 9 + f] : 0.f;
        }
    }
}

__global__ void k_bscan(const int* __restrict__ bhist, int* __restrict__ bstart,
                        int* __restrict__ bfill) {
    int t = threadIdx.x;
    int v = bhist[t];
    int ex = block_excl_scan256(v, t);
    bstart[t] = ex;
    bfill[t] = ex;
    if (t == 255) bstart[NBUCK] = ex + v;  // == N_EDGES
}

// bin edges into bucket regions of temp[]; payload packed 4B: (dst&255)<<16 | src
__global__ __launch_bounds__(256) void k_binfill(const int* __restrict__ src,
                                                 const int* __restrict__ dst,
                                                 int* __restrict__ bfill,
                                                 unsigned* __restrict__ temp) {
    __shared__ int h[NBUCK], gp[NBUCK], rk[NBUCK];
    int t = threadIdx.x;
    h[t] = 0; rk[t] = 0;
    __syncthreads();
    int base = blockIdx.x * BINBLK;
    int ss[16], dd[16];
    #pragma unroll
    for (int i = 0; i < 16; i++) {
        int e = base + i * 256 + t;
        bool ok = e < N_EDGES;
        ss[i] = ok ? src[e] : 0;
        dd[i] = ok ? dst[e] : -1;
        if (ok) atomicAdd(&h[dd[i] >> BUCK_SHIFT], 1);
    }
    __syncthreads();
    if (h[t]) gp[t] = atomicAdd(&bfill[t], h[t]);
    __syncthreads();
    #pragma unroll
    for (int i = 0; i < 16; i++) {
        if (dd[i] >= 0) {
            int b = dd[i] >> BUCK_SHIFT;
            int r = atomicAdd(&rk[b], 1);
            temp[gp[b] + r] = ((unsigned)(dd[i] & 255) << 16) | (unsigned)ss[i];
        }
    }
}

// one block per bucket: per-node counts/offsets/dis in LDS, then confined scatter
__global__ __launch_bounds__(256) void k_csrbuild(const unsigned* __restrict__ temp,
                                                  const int* __restrict__ bstart,
                                                  int* __restrict__ offs,
                                                  float* __restrict__ dis,
                                                  int* __restrict__ csr_src) {
    __shared__ int cnt[256], loff[256], rk[256];
    int b = blockIdx.x, t = threadIdx.x;
    int e0 = bstart[b], e1 = bstart[b + 1];
    int n0 = b << BUCK_SHIFT;
    cnt[t] = 0; rk[t] = 0;
    __syncthreads();
    for (int e = e0 + t; e < e1; e += 256)
        atomicAdd(&cnt[temp[e] >> 16], 1);
    __syncthreads();
    int c = cnt[t];
    int ex = block_excl_scan256(c, t);
    loff[t] = ex;
    int n = n0 + t;
    if (n < N_NODES) {
        offs[n] = e0 + ex;
        dis[n] = rsqrtf((float)c + 1.0f);
    }
    if (b == 0 && t == 0) offs[N_NODES] = N_EDGES;
    __syncthreads();
    for (int e = e0 + t; e < e1; e += 256) {
        unsigned v = temp[e];
        int li = v >> 16;
        int r = atomicAdd(&rk[li], 1);
        csr_src[e0 + loff[li] + r] = (int)(v & 0xffffu);
    }
}

// ---------------- layer 1 aggregation in 16-dim padded space ----------------
// y[n] = dn * sum_e dis_s*x16[src] + dn^2*x16[n]
__global__ __launch_bounds__(256) void k_agg9(const float* __restrict__ x16,
                                              const int* __restrict__ offs,
                                              const int* __restrict__ csr_src,
                                              const float* __restrict__ dis,
                                              float* __restrict__ y) {
    int wv = threadIdx.x >> 6, lane = threadIdx.x & 63;
    int n = blockIdx.x * 4 + wv;
    if (n >= N_NODES) return;
    int slot = lane >> 4, fl = lane & 15;
    int e0 = offs[n], e1 = offs[n + 1];
    float acc = 0.f;
    for (int e = e0 + slot; e < e1; e += 16) {
        int ss[4]; float cc[4];
        #pragma unroll
        for (int i = 0; i < 4; i++) {
            int ei = e + i * 4;
            bool ok = ei < e1;
            ss[i] = ok ? csr_src[ei] : n;
            cc[i] = ok ? dis[ss[i]] : 0.f;
        }
        #pragma unroll
        for (int i = 0; i < 4; i++)
            acc += cc[i] * x16[(size_t)ss[i] * 16 + fl];
    }
    acc += __shfl_xor(acc, 16, 64);
    acc += __shfl_xor(acc, 32, 64);
    float dn = dis[n];
    acc = dn * acc + dn * dn * x16[(size_t)n * 16 + fl];
    if (slot == 0) y[(size_t)n * 16 + fl] = acc;
}

// ---------------- fused layer1-gemm + relu + layer2-gemm ----------------
// out = bf16( relu(y16 @ W1 + b1) @ W2 ), linear [N][128] bf16
__global__ __launch_bounds__(256) void k_fused12(const float* __restrict__ y16,
                                                 const float* __restrict__ W1,
                                                 const float* __restrict__ b1,
                                                 const float* __restrict__ W2,
                                                 uint2* __restrict__ out8) {
    __shared__ float htile[64 * 128];
    __shared__ float ytile[64 * 16];
    int t = threadIdx.x;
    int n0 = blockIdx.x * 64;
    ((float4*)ytile)[t] = ((const float4*)(y16 + (size_t)n0 * 16))[t];
    __syncthreads();
    int q = t & 31;
    int tn = t >> 5;
    const float4* W14 = (const float4*)W1;
    float4 w1q[9];
    #pragma unroll
    for (int k = 0; k < 9; k++) w1q[k] = W14[k * 32 + q];
    float4 bq = ((const float4*)b1)[q];
    #pragma unroll
    for (int r = 0; r < 8; r++) {
        int row = tn * 8 + r;
        float4 a = bq;
        #pragma unroll
        for (int k = 0; k < 9; k++) {
            float yv = ytile[row * 16 + k];
            a.x += yv * w1q[k].x; a.y += yv * w1q[k].y;
            a.z += yv * w1q[k].z; a.w += yv * w1q[k].w;
        }
        *(float4*)&htile[row * 128 + 4 * q] =
            make_float4(fmaxf(a.x, 0.f), fmaxf(a.y, 0.f),
                        fmaxf(a.z, 0.f), fmaxf(a.w, 0.f));
    }
    __syncthreads();
    float4 acc[8];
    #pragma unroll
    for (int r = 0; r < 8; r++) acc[r] = make_float4(0.f, 0.f, 0.f, 0.f);
    const float4* W4 = (const float4*)W2;
    for (int k = 0; k < 128; k += 2) {
        float4 w0 = W4[k * 32 + q];
        float4 w1 = W4[(k + 1) * 32 + q];
        #pragma unroll
        for (int r = 0; r < 8; r++) {
            int row = tn * 8 + r;
            float2 hk = *(const float2*)&htile[row * 128 + k];
            acc[r].x += hk.x * w0.x; acc[r].y += hk.x * w0.y;
            acc[r].z += hk.x * w0.z; acc[r].w += hk.x * w0.w;
            acc[r].x += hk.y * w1.x; acc[r].y += hk.y * w1.y;
            acc[r].z += hk.y * w1.z; acc[r].w += hk.y * w1.w;
        }
    }
    #pragma unroll
    for (int r = 0; r < 8; r++) {
        int n = n0 + tn * 8 + r;
        if (n < N_NODES) out8[(size_t)n * 32 + q] = f4_to_bf4(acc[r]);
    }
}

// ---------------- bf16 gather-agg (layer 2), round-10 proven shape ----------
// wave-per-node: lane = 4 bf16 (8B), 32 lanes/row, 2 edges per load slot,
// 16 rows in flight; coef gathered from L2-resident dis
__global__ __launch_bounds__(256) void k_agg2(const uint2* __restrict__ h8,
                                              const int* __restrict__ offs,
                                              const int* __restrict__ csr_src,
                                              const float* __restrict__ dis,
                                              const float* __restrict__ bias,
                                              uint2* __restrict__ out) {
    int wv = threadIdx.x >> 6, lane = threadIdx.x & 63;
    int n = blockIdx.x * 4 + wv;
    if (n >= N_NODES) return;
    int half = lane >> 5;
    int fl = lane & 31;
    int e0 = offs[n], e1 = offs[n + 1];
    float4 acc = make_float4(0.f, 0.f, 0.f, 0.f);
    for (int e = e0 + half; e < e1; e += 16) {
        int ss[8]; float cc[8];
        #pragma unroll
        for (int i = 0; i < 8; i++) {
            int ei = e + i * 2;
            bool ok = ei < e1;
            ss[i] = ok ? csr_src[ei] : n;
            cc[i] = ok ? dis[ss[i]] : 0.f;
        }
        uint2 rows[8];
        #pragma unroll
        for (int i = 0; i < 8; i++)
            rows[i] = h8[(size_t)ss[i] * 32 + fl];
        #pragma unroll
        for (int i = 0; i < 8; i++) {
            float4 r = bf4_to_f4(rows[i]);
            acc.x += cc[i] * r.x;
            acc.y += cc[i] * r.y;
            acc.z += cc[i] * r.z;
            acc.w += cc[i] * r.w;
        }
    }
    acc.x += __shfl_xor(acc.x, 32, 64);
    acc.y += __shfl_xor(acc.y, 32, 64);
    acc.z += __shfl_xor(acc.z, 32, 64);
    acc.w += __shfl_xor(acc.w, 32, 64);
    float dn = dis[n];
    float4 hv = bf4_to_f4(h8[(size_t)n * 32 + fl]);
    acc.x = dn * acc.x + dn * dn * hv.x + bias[4 * fl];
    acc.y = dn * acc.y + dn * dn * hv.y + bias[4 * fl + 1];
    acc.z = dn * acc.z + dn * dn * hv.z + bias[4 * fl + 2];
    acc.w = dn * acc.w + dn * dn * hv.w + bias[4 * fl + 3];
    acc.x = fmaxf(acc.x, 0.f);
    acc.y = fmaxf(acc.y, 0.f);
    acc.z = fmaxf(acc.z, 0.f);
    acc.w = fmaxf(acc.w, 0.f);
    if (half == 0) out[(size_t)n * 32 + fl] = f4_to_bf4(acc);
}

// ---------------- layer-3 agg fused with mean-pool accumulation --------------
__global__ __launch_bounds__(256) void k_aggp(const uint2* __restrict__ h8,
                                              const int* __restrict__ offs,
                                              const int* __restrict__ csr_src,
                                              const float* __restrict__ dis,
                                              const int* __restrict__ batch,
                                              float* __restrict__ sums) {
    __shared__ float red[4][128];
    __shared__ int gid[4];
    int wv = threadIdx.x >> 6, lane = threadIdx.x & 63;
    int n = blockIdx.x * 4 + wv;     // N_NODES == 12500*4, no tail
    int half = lane >> 5;
    int fl = lane & 31;
    int e0 = offs[n], e1 = offs[n + 1];
    float4 acc = make_float4(0.f, 0.f, 0.f, 0.f);
    for (int e = e0 + half; e < e1; e += 16) {
        int ss[8]; float cc[8];
        #pragma unroll
        for (int i = 0; i < 8; i++) {
            int ei = e + i * 2;
            bool ok = ei < e1;
            ss[i] = ok ? csr_src[ei] : n;
            cc[i] = ok ? dis[ss[i]] : 0.f;
        }
        uint2 rows[8];
        #pragma unroll
        for (int i = 0; i < 8; i++)
            rows[i] = h8[(size_t)ss[i] * 32 + fl];
        #pragma unroll
        for (int i = 0; i < 8; i++) {
            float4 r = bf4_to_f4(rows[i]);
            acc.x += cc[i] * r.x;
            acc.y += cc[i] * r.y;
            acc.z += cc[i] * r.z;
            acc.w += cc[i] * r.w;
        }
    }
    acc.x += __shfl_xor(acc.x, 32, 64);
    acc.y += __shfl_xor(acc.y, 32, 64);
    acc.z += __shfl_xor(acc.z, 32, 64);
    acc.w += __shfl_xor(acc.w, 32, 64);
    float dn = dis[n];
    float4 hv = bf4_to_f4(h8[(size_t)n * 32 + fl]);
    acc.x = dn * acc.x + dn * dn * hv.x;
    acc.y = dn * acc.y + dn * dn * hv.y;
    acc.z = dn * acc.z + dn * dn * hv.z;
    acc.w = dn * acc.w + dn * dn * hv.w;
    if (half == 0) *(float4*)&red[wv][4 * fl] = acc;
    if (lane == 0) gid[wv] = batch[n];
    __syncthreads();
    int t = threadIdx.x;
    if (t < 128) {
        int g0 = gid[0], g1 = gid[1], g2 = gid[2], g3 = gid[3];
        float v0 = red[0][t], v1 = red[1][t], v2 = red[2][t], v3 = red[3][t];
        if (g0 == g3) {  // sorted batch -> all four equal
            atomicAdd(&sums[g0 * 128 + t], v0 + v1 + v2 + v3);
        } else {
            atomicAdd(&sums[g0 * 128 + t], v0);
            atomicAdd(&sums[g1 * 128 + t], v1);
            atomicAdd(&sums[g2 * 128 + t], v2);
            atomicAdd(&sums[g3 * 128 + t], v3);
        }
    }
}

// ---------------- final: counts via binary search + tiny GEMM ----------------
__global__ void k_final(const float* __restrict__ sums, const int* __restrict__ batch,
                        const float* __restrict__ W3, const float* __restrict__ b3,
                        float* __restrict__ out) {
    int idx = blockIdx.x * blockDim.x + threadIdx.x;
    if (idx >= N_GRAPHS * HID) return;
    int g = idx >> 7, j = idx & 127;
    int lo = 0, hi = N_NODES;
    while (lo < hi) { int m = (lo + hi) >> 1; if (batch[m] <= g) lo = m + 1; else hi = m; }
    int ub_g = lo;
    lo = 0; hi = N_NODES;
    int gm1 = g - 1;
    while (lo < hi) { int m = (lo + hi) >> 1; if (batch[m] <= gm1) lo = m + 1; else hi = m; }
    int cnt = ub_g - lo;
    float inv = 1.0f / fmaxf((float)cnt, 1.0f);
    const float* srow = sums + g * 128;
    float acc = 0.f;
    for (int k = 0; k < 128; k++) acc += srow[k] * W3[k * 128 + j];
    out[idx] = acc * inv + b3[j];
}

extern "C" void kernel_launch(void* const* d_in, const int* in_sizes, int n_in,
                              void* d_out, int out_size, void* d_ws, size_t ws_size,
                              hipStream_t stream) {
    const float* x     = (const float*)d_in[0];
    const int*   ei    = (const int*)d_in[1];
    const int*   batch = (const int*)d_in[2];
    const float* W1    = (const float*)d_in[3];
    const float* b1    = (const float*)d_in[4];
    const float* W2    = (const float*)d_in[5];
    const float* b2    = (const float*)d_in[6];
    const float* W3    = (const float*)d_in[7];
    const float* b3    = (const float*)d_in[8];
    float* out = (float*)d_out;
    const int* src = ei;
    const int* dst = ei + N_EDGES;

    char* ws = (char*)d_ws;
    size_t off = 0;
    auto alloc = [&](size_t bytes) -> void* {
        void* p = ws + off;
        off += (bytes + 255) & ~(size_t)255;
        return p;
    };
    int*      bhist   = (int*)alloc((size_t)NBUCK * 4);              // | adjacent:
    float*    sums    = (float*)alloc((size_t)N_GRAPHS * 128 * 4);   // | one memset
    unsigned* hb1     = (unsigned*)alloc((size_t)N_NODES * 64 * 4);  // bf16 [N][128]
    unsigned* hb2     = (unsigned*)alloc((size_t)N_NODES * 64 * 4);  // bf16 [N][128]
    unsigned* temp    = (unsigned*)alloc((size_t)N_EDGES * 4);       // packed (ldst<<16|src)
    int*      csr_src = (int*)alloc((size_t)N_EDGES * 4);
    int*      bstart  = (int*)alloc((size_t)(NBUCK + 1) * 4);
    int*      bfill   = (int*)alloc((size_t)NBUCK * 4);
    int*      offs    = (int*)alloc((size_t)(N_NODES + 1) * 4);
    float*    dis     = (float*)alloc((size_t)N_NODES * 4);
    float*    x16     = (float*)alloc((size_t)N_NODES * 16 * 4);
    float*    y16     = (float*)alloc((size_t)(N_NODES + 64) * 16 * 4);  // +pad for tile overread

    // bhist (1KB, 256-aligned) and sums (128KB) are adjacent -> single memset
    hipMemsetAsync(bhist, 0, (size_t)NBUCK * 4 + (size_t)N_GRAPHS * 128 * 4, stream);

    k_bhist_pad<<<BHIST_NB + PAD_NB, 256, 0, stream>>>(dst, bhist, x, x16);
    k_bscan<<<1, 256, 0, stream>>>(bhist, bstart, bfill);
    k_binfill<<<BHIST_NB, 256, 0, stream>>>(src, dst, bfill, temp);
    k_csrbuild<<<NBUCK_USED, 256, 0, stream>>>(temp, bstart, offs, dis, csr_src);

    // layer 1 aggregate in 9-dim space, then fused GEMMs -> hb1 = bf16(relu(y@W1+b1)@W2)
    k_agg9<<<(N_NODES + 3) / 4, 256, 0, stream>>>(x16, offs, csr_src, dis, y16);
    k_fused12<<<(N_NODES + 63) / 64, 256, 0, stream>>>(y16, W1, b1, W2, (uint2*)hb1);
    // layer 2 agg: hb2 = bf16(relu(agg(hb1) + b2))
    k_agg2<<<N_NODES / 4, 256, 0, stream>>>((const uint2*)hb1, offs, csr_src, dis,
                                            b2, (uint2*)hb2);
    // layer 3 agg fused with pooling (W3 deferred): sums += per-graph agg rows
    k_aggp<<<N_NODES / 4, 256, 0, stream>>>((const uint2*)hb2, offs, csr_src, dis,
                                            batch, sums);
    // final tiny GEMM with inline counts
    k_final<<<(N_GRAPHS * HID + 255) / 256, 256, 0, stream>>>(sums, batch, W3, b3, out);
}